// Round 6
// baseline (253.958 us; speedup 1.0000x reference)
//
#include <hip/hip_runtime.h>
#include <hip/hip_bf16.h>
#include <cstdint>
#include <cstddef>

#define HIDDEN   2048
#define NH       16
#define NKV      4
#define HD       128
#define SEQ      2048
#define BATCH    2
#define NTOK     (BATCH*SEQ)      // 4096
#define QKV_LD   3072             // Q(2048) | K(512) | V(512)
#define KOFF     2048
#define VOFF     2560
#define SM_SCALE 0.08838834764831845f   // 1/sqrt(128)
#define LOG2E    1.4426950408889634f

typedef __attribute__((ext_vector_type(8)))  short bf16x8;
typedef __attribute__((ext_vector_type(4)))  float f32x4v;
typedef __attribute__((ext_vector_type(16))) float f32x16;
typedef unsigned short ushort_t;

__device__ __forceinline__ unsigned short f2bf(float f) {
  return __builtin_bit_cast(unsigned short, __float2bfloat16(f));
}
__device__ __forceinline__ float bf2f(ushort_t u) {
  return __builtin_bit_cast(float, (unsigned)u << 16);
}
__device__ __forceinline__ unsigned pack2(float a, float b) {
  return (unsigned)f2bf(a) | ((unsigned)f2bf(b) << 16);
}

// async global->LDS, 16B/lane; LDS dest lane-linear, swizzle realized on the GLOBAL src.
__device__ __forceinline__ void gload16(const void* g, void* l) {
  __builtin_amdgcn_global_load_lds(
      (const __attribute__((address_space(1))) unsigned int*)g,
      (__attribute__((address_space(3))) unsigned int*)l, 16, 0, 0);
}

// ---------------- conversion kernels ----------------
__global__ __launch_bounds__(256) void conv_f2b(
    const float* __restrict__ in, ushort_t* __restrict__ out, int n8)
{
  const int i = blockIdx.x*256 + threadIdx.x;
  if (i >= n8) return;
  const float4 a = ((const float4*)in)[2*i];
  const float4 b = ((const float4*)in)[2*i + 1];
  uint4 r;
  r.x = pack2(a.x, a.y); r.y = pack2(a.z, a.w);
  r.z = pack2(b.x, b.y); r.w = pack2(b.z, b.w);
  ((uint4*)out)[i] = r;
}

// W[K][N] fp32 -> Wt[N][K] bf16
__global__ __launch_bounds__(256) void transpose_f2b(
    const float* __restrict__ W, ushort_t* __restrict__ Wt, int K, int N)
{
  __shared__ float tile[32][33];
  const int n0 = blockIdx.x*32, k0 = blockIdx.y*32;
  const int tx = threadIdx.x & 31, ty = threadIdx.x >> 5;
  #pragma unroll
  for (int i = 0; i < 4; ++i)
    tile[ty*4 + i][tx] = W[(size_t)(k0 + ty*4 + i)*N + n0 + tx];
  __syncthreads();
  #pragma unroll
  for (int i = 0; i < 4; ++i) {
    const int nl = ty*4 + i;
    Wt[(size_t)(n0 + nl)*K + k0 + tx] = f2bf(tile[tx][nl]);
  }
}

// ---------------- bf16 MFMA GEMM (m97 structure), templated output dtype --------
template<bool B16OUT>
__global__ __launch_bounds__(256) void bt_gemm(
    const ushort_t* __restrict__ A, const ushort_t* __restrict__ Bt,
    void* __restrict__ Cv, int ldc)
{
  __shared__ ushort_t As[128*64];
  __shared__ ushort_t Bs[128*64];
  const int t = threadIdx.x, lane = t & 63, w = t >> 6;
  const int bm = blockIdx.y*128, bn = blockIdx.x*128;
  const int wr = w >> 1, wc = w & 1;
  const int lr = lane & 15, lg = lane >> 4;

  f32x4v acc[4][4];
  #pragma unroll
  for (int fm = 0; fm < 4; ++fm)
    #pragma unroll
    for (int fn = 0; fn < 4; ++fn)
      #pragma unroll
      for (int r = 0; r < 4; ++r) acc[fm][fn][r] = 0.f;

  const char* Ab = (const char*)A;
  const char* Bb = (const char*)Bt;
  char* asb = (char*)As;
  char* bsb = (char*)Bs;

  for (int kt = 0; kt < HIDDEN*2; kt += 128) {
    __syncthreads();
    #pragma unroll
    for (int u = 0; u < 4; ++u) {
      const int idx = u*256 + t;
      const int row = idx >> 3;
      const int kb  = (idx & 7) * 16;
      const int skb = kb ^ ((row & 7) << 4);
      gload16(Ab + (size_t)(bm + row)*4096 + kt + skb, asb + idx*16);
      gload16(Bb + (size_t)(bn + row)*4096 + kt + skb, bsb + idx*16);
    }
    __syncthreads();
    #pragma unroll
    for (int kc = 0; kc < 2; ++kc) {
      bf16x8 af[4], bfr[4];
      #pragma unroll
      for (int f = 0; f < 4; ++f) {
        const int rm = wr*64 + f*16 + lr;
        af[f]  = *(const bf16x8*)(asb + rm*128 + ((kc*64 + lg*16) ^ ((rm & 7) << 4)));
        const int rn = wc*64 + f*16 + lr;
        bfr[f] = *(const bf16x8*)(bsb + rn*128 + ((kc*64 + lg*16) ^ ((rn & 7) << 4)));
      }
      #pragma unroll
      for (int fm = 0; fm < 4; ++fm)
        #pragma unroll
        for (int fn = 0; fn < 4; ++fn)
          acc[fm][fn] = __builtin_amdgcn_mfma_f32_16x16x32_bf16(af[fm], bfr[fn], acc[fm][fn], 0, 0, 0);
    }
  }

  #pragma unroll
  for (int fm = 0; fm < 4; ++fm) {
    const int m = bm + wr*64 + fm*16 + lg*4;
    #pragma unroll
    for (int fn = 0; fn < 4; ++fn) {
      const int n = bn + wc*64 + fn*16 + lr;
      #pragma unroll
      for (int r = 0; r < 4; ++r) {
        if constexpr (B16OUT)
          ((ushort_t*)Cv)[(size_t)(m + r)*ldc + n] = f2bf(acc[fm][fn][r]);
        else
          ((float*)Cv)[(size_t)(m + r)*ldc + n] = acc[fm][fn][r];
      }
    }
  }
}

// RoPE on bf16 QKV; writes Qo (SM_SCALE*LOG2E folded -> softmax in exp2 domain)
// and Ko[b,hk][s][d].
__global__ __launch_bounds__(256) void rope_conv(
    const ushort_t* __restrict__ QKVb, ushort_t* __restrict__ Qo,
    ushort_t* __restrict__ Ko)
{
  const int total = NTOK * (NH + NKV) * (HD/2);
  int idx = blockIdx.x * 256 + threadIdx.x;
  if (idx >= total) return;
  const int i   = idx & 63;
  int tmp = idx >> 6;
  const int hs  = tmp % (NH + NKV);
  const int tkn = tmp / (NH + NKV);
  const int s   = tkn & (SEQ - 1);
  const int b   = tkn >> 11;
  const float invf = expf(-(float)i * 0.14391156831212787f);
  float sn, cs;
  sincosf((float)s * invf, &sn, &cs);
  const size_t base = (size_t)tkn * QKV_LD + (hs < NH ? hs * HD : KOFF + (hs - NH) * HD);
  const float x0 = bf2f(QKVb[base + i]);
  const float x1 = bf2f(QKVb[base + i + 64]);
  const float y0 = x0 * cs - x1 * sn;
  const float y1 = x1 * cs + x0 * sn;
  if (hs < NH) {
    ushort_t* q = Qo + (size_t)tkn * HIDDEN + hs * HD;
    q[i]      = f2bf(y0 * (SM_SCALE * LOG2E));
    q[i + 64] = f2bf(y1 * (SM_SCALE * LOG2E));
  } else {
    ushort_t* k = Ko + ((size_t)(b*NKV + (hs - NH))*SEQ + s) * HD;
    k[i]      = f2bf(y0);
    k[i + 64] = f2bf(y1);
  }
}

// V columns of QKVb -> Vtb[b,hk][d][s]
__global__ __launch_bounds__(256) void vt_conv(
    const ushort_t* __restrict__ QKVb, ushort_t* __restrict__ Vtb)
{
  __shared__ ushort_t tile[32][33];
  const int s0 = blockIdx.x*32;
  const int d0 = (blockIdx.y & 3)*32;
  const int bk = blockIdx.y >> 2;
  const int b = bk >> 2, hk = bk & 3;
  const int tx = threadIdx.x & 31, ty = threadIdx.x >> 5;
  #pragma unroll
  for (int i = 0; i < 4; ++i) {
    const int sl = ty*4 + i;
    tile[sl][tx] = QKVb[(size_t)(b*SEQ + s0 + sl)*QKV_LD + VOFF + hk*HD + d0 + tx];
  }
  __syncthreads();
  #pragma unroll
  for (int i = 0; i < 4; ++i) {
    const int dl = ty*4 + i;
    Vtb[((size_t)bk*HD + d0 + dl)*SEQ + s0 + tx] = tile[tx][dl];
  }
}

// ---------------- MFMA flash attention v3 ----------------
// q-tile = 64 rows, block = 2 waves (128 thr). Block bx handles the pair
// {bx, 31-bx} -> 33 K-tile stagings each, 512 uniform blocks = 2 blocks/CU =
// 2 waves/SIMD (wave A's MFMA overlaps wave B's softmax VALU).
// Softmax in exp2 domain (log2e folded into Q); T13 defer-max rescale.
__global__ __launch_bounds__(128) void attn_mfma3(
    const ushort_t* __restrict__ Qb, const ushort_t* __restrict__ Kb,
    const ushort_t* __restrict__ Vtb, ushort_t* __restrict__ O)
{
  __shared__ ushort_t Kl[2][64*128];
  __shared__ ushort_t Vl[2][128*64];
  __shared__ ushort_t Pl[2][32*64];     // 72 KB total

  const int bx = blockIdx.x, bh = blockIdx.y;
  const int b = bh >> 4, h = bh & 15, hk = h >> 2;
  const int t = threadIdx.x, w = t >> 6, lane = t & 63;
  const int c = lane & 31, hi = lane >> 5;

  const char* Kbb = (const char*)(Kb + (size_t)(b*NKV + hk)*SEQ*HD);
  const char* Vbb = (const char*)(Vtb + (size_t)(b*NKV + hk)*HD*SEQ);
  char* plb = (char*)Pl[w];

  // per-thread staging offsets (128 threads -> 8 slots each per K and V tile)
  int ksrc[8], vsrc[8], ldst[8];
  #pragma unroll
  for (int u = 0; u < 8; ++u) {
    const int idx = u*128 + t;
    const int krow = idx >> 4, kof = (idx & 15) << 4;   // K tile: 64 rows x 256B
    ksrc[u] = krow*256 + (kof ^ ((krow & 15) << 4));
    const int vd = idx >> 3,  vof = (idx & 7) << 4;     // V tile: 128 rows x 128B
    vsrc[u] = vd*(SEQ*2) + (vof ^ ((vd & 7) << 4));
    ldst[u] = idx*16;
  }

  #pragma unroll 1
  for (int pi = 0; pi < 2; ++pi) {
    const int qb  = pi ? (31 - bx) : bx;
    const int qw0 = qb*64 + w*32;
    const int qg  = qw0 + c;

    bf16x8 qf[8];
    {
      const ushort_t* qrow = Qb + (size_t)(b*SEQ + qg)*HIDDEN + h*HD;
      #pragma unroll
      for (int kc = 0; kc < 8; ++kc)
        qf[kc] = *(const bf16x8*)(qrow + kc*16 + hi*8);
    }

    f32x16 ot[4];
    #pragma unroll
    for (int nc = 0; nc < 4; ++nc)
      #pragma unroll
      for (int r = 0; r < 16; ++r) ot[nc][r] = 0.f;
    float m = -1e30f, l = 0.f;

    // prologue: stage tile 0 into buf 0
    #pragma unroll
    for (int u = 0; u < 8; ++u) {
      gload16(Kbb + ksrc[u], (char*)Kl[0] + ldst[u]);
      gload16(Vbb + vsrc[u], (char*)Vl[0] + ldst[u]);
    }
    __syncthreads();

    int cur = 0;
    for (int kt = 0; kt <= qb; ++kt) {
      if (kt < qb) {       // issue next-tile loads; they overlap current compute
        const int nb = cur ^ 1;
        const size_t kto = (size_t)(kt + 1) * 16384;   // 64 rows * 256B
        const int    vto = (kt + 1) * 128;             // 64 keys * 2B within V rows
        #pragma unroll
        for (int u = 0; u < 8; ++u) {
          gload16(Kbb + kto + ksrc[u], (char*)Kl[nb] + ldst[u]);
          gload16(Vbb + vto + vsrc[u], (char*)Vl[nb] + ldst[u]);
        }
      }
      {
        const char* klb = (const char*)Kl[cur];
        const char* vlb = (const char*)Vl[cur];
        // ---- QK^T (swapped): D col = q-row, rows = keys
        f32x16 s[2];
        #pragma unroll
        for (int kn = 0; kn < 2; ++kn)
          #pragma unroll
          for (int r = 0; r < 16; ++r) s[kn][r] = 0.f;
        #pragma unroll
        for (int kn = 0; kn < 2; ++kn) {
          const int row = kn*32 + c;
          const int sw = (row & 15) << 4;
          #pragma unroll
          for (int kc = 0; kc < 8; ++kc) {
            const bf16x8 ka = *(const bf16x8*)(klb + row*256 + ((kc*32 + hi*16) ^ sw));
            s[kn] = __builtin_amdgcn_mfma_f32_32x32x16_bf16(ka, qf[kc], s[kn], 0, 0, 0);
          }
        }
        // ---- causal mask: only the diagonal tile (kt == qb) needs it
        if (kt == qb) {
          #pragma unroll
          for (int kn = 0; kn < 2; ++kn)
            #pragma unroll
            for (int r = 0; r < 16; ++r) {
              const int kg_ = kt*64 + kn*32 + (r & 3) + 8*(r >> 2) + 4*hi;
              if (kg_ > qg) s[kn][r] = -1e30f;
            }
        }
        // ---- online softmax (exp2 domain, lane-local per q-row)
        float mx[16];
        #pragma unroll
        for (int r = 0; r < 16; ++r) mx[r] = fmaxf(s[0][r], s[1][r]);
        #pragma unroll
        for (int st = 8; st > 0; st >>= 1)
          #pragma unroll
          for (int r = 0; r < 8; ++r)
            if (r < st) mx[r] = fmaxf(mx[r], mx[r + st]);
        const float pm = fmaxf(mx[0], __shfl_xor(mx[0], 32));
        // T13 defer-max: skip O/l rescale while max growth <= 8 (P <= 2^8, fp32-safe)
        if (!__all(pm - m <= 8.f)) {
          const float mnew = fmaxf(m, pm);
          const float corr = exp2f(m - mnew);
          m = mnew;
          l *= corr;
          #pragma unroll
          for (int nc = 0; nc < 4; ++nc) ot[nc] *= corr;
        }
        float ls = 0.f;
        #pragma unroll
        for (int kn = 0; kn < 2; ++kn)
          #pragma unroll
          for (int r = 0; r < 16; ++r) {
            const float p = exp2f(s[kn][r] - m);
            ls += p;
            s[kn][r] = p;
          }
        l += ls;
        // ---- P^T -> Pl[qrow][key]
        {
          const int swp = (c & 7) << 4;
          #pragma unroll
          for (int kn = 0; kn < 2; ++kn)
            #pragma unroll
            for (int r = 0; r < 16; r += 2) {
              const int key = kn*32 + (r & 3) + 8*(r >> 2) + 4*hi;
              *(unsigned*)(plb + c*128 + ((key*2) ^ swp)) = pack2(s[kn][r], s[kn][r+1]);
            }
        }
        asm volatile("s_waitcnt lgkmcnt(0)" ::: "memory");   // own-wave Pl write->read
        // ---- PV: O^T += V^T . P^T
        #pragma unroll
        for (int kc = 0; kc < 4; ++kc) {
          const bf16x8 pb = *(const bf16x8*)(plb + c*128 + ((kc*32 + hi*16) ^ ((c & 7) << 4)));
          #pragma unroll
          for (int nc = 0; nc < 4; ++nc) {
            const int dim = nc*32 + c;
            const bf16x8 va = *(const bf16x8*)(vlb + dim*128 + ((kc*32 + hi*16) ^ ((dim & 7) << 4)));
            ot[nc] = __builtin_amdgcn_mfma_f32_32x32x16_bf16(va, pb, ot[nc], 0, 0, 0);
          }
        }
      }
      __syncthreads();   // staged loads drained (vmcnt0) + LDS reads done before overwrite
      cur ^= 1;
    }

    // ---- epilogue
    const float lt = l + __shfl_xor(l, 32);
    const float inv = 1.f / lt;
    ushort_t* orow = O + (size_t)(b*SEQ + qg) * HIDDEN + h*HD;
    #pragma unroll
    for (int nc = 0; nc < 4; ++nc)
      #pragma unroll
      for (int r = 0; r < 16; r += 2) {
        const int dim = nc*32 + (r & 3) + 8*(r >> 2) + 4*hi;
        *(unsigned*)(orow + dim) = pack2(ot[nc][r]*inv, ot[nc][r+1]*inv);
      }
  }
}

extern "C" void kernel_launch(void* const* d_in, const int* in_sizes, int n_in,
                              void* d_out, int out_size, void* d_ws, size_t ws_size,
                              hipStream_t stream)
{
  (void)in_sizes; (void)n_in; (void)out_size; (void)ws_size;
  const float* H  = (const float*)d_in[0];
  const float* Wq = (const float*)d_in[1];
  const float* Wk = (const float*)d_in[2];
  const float* Wv = (const float*)d_in[3];
  const float* Wo = (const float*)d_in[4];
  float* out = (float*)d_out;

  char* ws = (char*)d_ws;
  ushort_t* QKVb = (ushort_t*)ws;                      // [4096][3072] bf16  25.2 MB
  ushort_t* Hb   = (ushort_t*)(ws + 25165824);         // [4096][2048] bf16  16.8 MB (dead after gemm -> Qb)
  ushort_t* Qb   = Hb;
  ushort_t* Wt   = (ushort_t*)(ws + 41943040);         // [3072][2048] bf16  12.6 MB (reused for Wo)
  ushort_t* Kb   = (ushort_t*)(ws + 54525952);         // [2*4][2048][128]    4.2 MB
  ushort_t* Vtb  = (ushort_t*)(ws + 58720256);         // [2*4][128][2048]    4.2 MB
  ushort_t* Oat  = (ushort_t*)(ws + 62914560);         // [4096][2048] bf16  16.8 MB

  conv_f2b<<<4096, 256, 0, stream>>>(H, Hb, NTOK*HIDDEN/8);
  transpose_f2b<<<dim3(64, 64), 256, 0, stream>>>(Wq, Wt,                     2048, 2048);
  transpose_f2b<<<dim3(16, 64), 256, 0, stream>>>(Wk, Wt + (size_t)2048*2048, 2048, 512);
  transpose_f2b<<<dim3(16, 64), 256, 0, stream>>>(Wv, Wt + (size_t)2560*2048, 2048, 512);

  bt_gemm<true><<<dim3(QKV_LD/128, NTOK/128), 256, 0, stream>>>(Hb, Wt, QKVb, QKV_LD);

  const int rope_total = NTOK * (NH + NKV) * (HD/2);
  rope_conv<<<(rope_total + 255)/256, 256, 0, stream>>>(QKVb, Qb, Kb);
  vt_conv<<<dim3(SEQ/32, 32), 256, 0, stream>>>(QKVb, Vtb);

  attn_mfma3<<<dim3(16, 32), 128, 0, stream>>>(Qb, Kb, Vtb, Oat);

  transpose_f2b<<<dim3(64, 64), 256, 0, stream>>>(Wo, Wt, 2048, 2048);
  bt_gemm<false><<<dim3(HIDDEN/128, NTOK/128), 256, 0, stream>>>(Oat, Wt, out, HIDDEN);
}

// Round 7
// 244.157 us; speedup vs baseline: 1.0401x; 1.0401x over previous
//
#include <hip/hip_runtime.h>
#include <hip/hip_bf16.h>
#include <cstdint>
#include <cstddef>

#define HIDDEN   2048
#define NH       16
#define NKV      4
#define HD       128
#define SEQ      2048
#define BATCH    2
#define NTOK     (BATCH*SEQ)      // 4096
#define QKV_LD   3072             // Q(2048) | K(512) | V(512)
#define KOFF     2048
#define VOFF     2560
#define SM_SCALE 0.08838834764831845f   // 1/sqrt(128)
#define LOG2E    1.4426950408889634f

typedef __attribute__((ext_vector_type(8)))  short bf16x8;
typedef __attribute__((ext_vector_type(4)))  float f32x4v;
typedef __attribute__((ext_vector_type(16))) float f32x16;
typedef unsigned short ushort_t;

__device__ __forceinline__ unsigned short f2bf(float f) {
  return __builtin_bit_cast(unsigned short, __float2bfloat16(f));
}
__device__ __forceinline__ float bf2f(ushort_t u) {
  return __builtin_bit_cast(float, (unsigned)u << 16);
}
__device__ __forceinline__ unsigned pack2(float a, float b) {
  return (unsigned)f2bf(a) | ((unsigned)f2bf(b) << 16);
}

// async global->LDS, 16B/lane; LDS dest lane-linear, swizzle realized on the GLOBAL src.
__device__ __forceinline__ void gload16(const void* g, void* l) {
  __builtin_amdgcn_global_load_lds(
      (const __attribute__((address_space(1))) unsigned int*)g,
      (__attribute__((address_space(3))) unsigned int*)l, 16, 0, 0);
}

// ---------------- conversion kernels ----------------
__global__ __launch_bounds__(256) void conv_f2b(
    const float* __restrict__ in, ushort_t* __restrict__ out, int n8)
{
  const int i = blockIdx.x*256 + threadIdx.x;
  if (i >= n8) return;
  const float4 a = ((const float4*)in)[2*i];
  const float4 b = ((const float4*)in)[2*i + 1];
  uint4 r;
  r.x = pack2(a.x, a.y); r.y = pack2(a.z, a.w);
  r.z = pack2(b.x, b.y); r.w = pack2(b.z, b.w);
  ((uint4*)out)[i] = r;
}

// W[K][N] fp32 -> Wt[N][K] bf16
__global__ __launch_bounds__(256) void transpose_f2b(
    const float* __restrict__ W, ushort_t* __restrict__ Wt, int K, int N)
{
  __shared__ float tile[32][33];
  const int n0 = blockIdx.x*32, k0 = blockIdx.y*32;
  const int tx = threadIdx.x & 31, ty = threadIdx.x >> 5;
  #pragma unroll
  for (int i = 0; i < 4; ++i)
    tile[ty*4 + i][tx] = W[(size_t)(k0 + ty*4 + i)*N + n0 + tx];
  __syncthreads();
  #pragma unroll
  for (int i = 0; i < 4; ++i) {
    const int nl = ty*4 + i;
    Wt[(size_t)(n0 + nl)*K + k0 + tx] = f2bf(tile[tx][nl]);
  }
}

// ---------------- bf16 MFMA GEMM (m97 structure), templated output dtype --------
template<bool B16OUT>
__global__ __launch_bounds__(256) void bt_gemm(
    const ushort_t* __restrict__ A, const ushort_t* __restrict__ Bt,
    void* __restrict__ Cv, int ldc)
{
  __shared__ ushort_t As[128*64];
  __shared__ ushort_t Bs[128*64];
  const int t = threadIdx.x, lane = t & 63, w = t >> 6;
  const int bm = blockIdx.y*128, bn = blockIdx.x*128;
  const int wr = w >> 1, wc = w & 1;
  const int lr = lane & 15, lg = lane >> 4;

  f32x4v acc[4][4];
  #pragma unroll
  for (int fm = 0; fm < 4; ++fm)
    #pragma unroll
    for (int fn = 0; fn < 4; ++fn)
      #pragma unroll
      for (int r = 0; r < 4; ++r) acc[fm][fn][r] = 0.f;

  const char* Ab = (const char*)A;
  const char* Bb = (const char*)Bt;
  char* asb = (char*)As;
  char* bsb = (char*)Bs;

  for (int kt = 0; kt < HIDDEN*2; kt += 128) {
    __syncthreads();
    #pragma unroll
    for (int u = 0; u < 4; ++u) {
      const int idx = u*256 + t;
      const int row = idx >> 3;
      const int kb  = (idx & 7) * 16;
      const int skb = kb ^ ((row & 7) << 4);
      gload16(Ab + (size_t)(bm + row)*4096 + kt + skb, asb + idx*16);
      gload16(Bb + (size_t)(bn + row)*4096 + kt + skb, bsb + idx*16);
    }
    __syncthreads();
    #pragma unroll
    for (int kc = 0; kc < 2; ++kc) {
      bf16x8 af[4], bfr[4];
      #pragma unroll
      for (int f = 0; f < 4; ++f) {
        const int rm = wr*64 + f*16 + lr;
        af[f]  = *(const bf16x8*)(asb + rm*128 + ((kc*64 + lg*16) ^ ((rm & 7) << 4)));
        const int rn = wc*64 + f*16 + lr;
        bfr[f] = *(const bf16x8*)(bsb + rn*128 + ((kc*64 + lg*16) ^ ((rn & 7) << 4)));
      }
      #pragma unroll
      for (int fm = 0; fm < 4; ++fm)
        #pragma unroll
        for (int fn = 0; fn < 4; ++fn)
          acc[fm][fn] = __builtin_amdgcn_mfma_f32_16x16x32_bf16(af[fm], bfr[fn], acc[fm][fn], 0, 0, 0);
    }
  }

  #pragma unroll
  for (int fm = 0; fm < 4; ++fm) {
    const int m = bm + wr*64 + fm*16 + lg*4;
    #pragma unroll
    for (int fn = 0; fn < 4; ++fn) {
      const int n = bn + wc*64 + fn*16 + lr;
      #pragma unroll
      for (int r = 0; r < 4; ++r) {
        if constexpr (B16OUT)
          ((ushort_t*)Cv)[(size_t)(m + r)*ldc + n] = f2bf(acc[fm][fn][r]);
        else
          ((float*)Cv)[(size_t)(m + r)*ldc + n] = acc[fm][fn][r];
      }
    }
  }
}

// RoPE on bf16 QKV; writes Qo (SM_SCALE*LOG2E folded -> softmax in exp2 domain)
// and Ko[b,hk][s][d].
__global__ __launch_bounds__(256) void rope_conv(
    const ushort_t* __restrict__ QKVb, ushort_t* __restrict__ Qo,
    ushort_t* __restrict__ Ko)
{
  const int total = NTOK * (NH + NKV) * (HD/2);
  int idx = blockIdx.x * 256 + threadIdx.x;
  if (idx >= total) return;
  const int i   = idx & 63;
  int tmp = idx >> 6;
  const int hs  = tmp % (NH + NKV);
  const int tkn = tmp / (NH + NKV);
  const int s   = tkn & (SEQ - 1);
  const int b   = tkn >> 11;
  const float invf = expf(-(float)i * 0.14391156831212787f);
  float sn, cs;
  sincosf((float)s * invf, &sn, &cs);
  const size_t base = (size_t)tkn * QKV_LD + (hs < NH ? hs * HD : KOFF + (hs - NH) * HD);
  const float x0 = bf2f(QKVb[base + i]);
  const float x1 = bf2f(QKVb[base + i + 64]);
  const float y0 = x0 * cs - x1 * sn;
  const float y1 = x1 * cs + x0 * sn;
  if (hs < NH) {
    ushort_t* q = Qo + (size_t)tkn * HIDDEN + hs * HD;
    q[i]      = f2bf(y0 * (SM_SCALE * LOG2E));
    q[i + 64] = f2bf(y1 * (SM_SCALE * LOG2E));
  } else {
    ushort_t* k = Ko + ((size_t)(b*NKV + (hs - NH))*SEQ + s) * HD;
    k[i]      = f2bf(y0);
    k[i + 64] = f2bf(y1);
  }
}

// V columns of QKVb -> Vtb[b,hk][d][s]
__global__ __launch_bounds__(256) void vt_conv(
    const ushort_t* __restrict__ QKVb, ushort_t* __restrict__ Vtb)
{
  __shared__ ushort_t tile[32][33];
  const int s0 = blockIdx.x*32;
  const int d0 = (blockIdx.y & 3)*32;
  const int bk = blockIdx.y >> 2;
  const int b = bk >> 2, hk = bk & 3;
  const int tx = threadIdx.x & 31, ty = threadIdx.x >> 5;
  #pragma unroll
  for (int i = 0; i < 4; ++i) {
    const int sl = ty*4 + i;
    tile[sl][tx] = QKVb[(size_t)(b*SEQ + s0 + sl)*QKV_LD + VOFF + hk*HD + d0 + tx];
  }
  __syncthreads();
  #pragma unroll
  for (int i = 0; i < 4; ++i) {
    const int dl = ty*4 + i;
    Vtb[((size_t)bk*HD + d0 + dl)*SEQ + s0 + tx] = tile[tx][dl];
  }
}

// ---------------- MFMA flash attention v4 ----------------
// q-tile = 64 rows, block = 2 waves (128 thr), single-buffered K/V (40 KB LDS)
// -> 4 blocks/CU resident, grid 1024 blocks = 8 waves/CU = 2 waves/SIMD.
// No pairing: block (bh = blockIdx.x, qb = 31 - blockIdx.y); round-robin CU
// assignment spreads qb by +8 per CU -> per-CU work spread only ~1.2x.
// TLP across the 4 resident blocks hides the single-buffer stage latency.
__global__ __launch_bounds__(128) void attn_mfma4(
    const ushort_t* __restrict__ Qb, const ushort_t* __restrict__ Kb,
    const ushort_t* __restrict__ Vtb, ushort_t* __restrict__ O)
{
  __shared__ ushort_t Kl[64*128];
  __shared__ ushort_t Vl[128*64];
  __shared__ ushort_t Pl[2][32*64];     // 40 KB total

  const int bh = blockIdx.x;
  const int qb = 31 - blockIdx.y;       // big tiles first in dispatch order
  const int b = bh >> 4, h = bh & 15, hk = h >> 2;
  const int t = threadIdx.x, w = t >> 6, lane = t & 63;
  const int c = lane & 31, hi = lane >> 5;
  const int qw0 = qb*64 + w*32;
  const int qg  = qw0 + c;

  const char* Kbb = (const char*)(Kb + (size_t)(b*NKV + hk)*SEQ*HD);
  const char* Vbb = (const char*)(Vtb + (size_t)(b*NKV + hk)*HD*SEQ);
  char* plb = (char*)Pl[w];
  char* klds = (char*)Kl;
  char* vlds = (char*)Vl;

  // per-thread staging offsets (128 threads -> 8 slots each per K and V tile)
  int ksrc[8], vsrc[8], ldst[8];
  #pragma unroll
  for (int u = 0; u < 8; ++u) {
    const int idx = u*128 + t;
    const int krow = idx >> 4, kof = (idx & 15) << 4;   // K tile: 64 rows x 256B
    ksrc[u] = krow*256 + (kof ^ ((krow & 15) << 4));
    const int vd = idx >> 3,  vof = (idx & 7) << 4;     // V tile: 128 rows x 128B
    vsrc[u] = vd*(SEQ*2) + (vof ^ ((vd & 7) << 4));
    ldst[u] = idx*16;
  }

  bf16x8 qf[8];
  {
    const ushort_t* qrow = Qb + (size_t)(b*SEQ + qg)*HIDDEN + h*HD;
    #pragma unroll
    for (int kc = 0; kc < 8; ++kc)
      qf[kc] = *(const bf16x8*)(qrow + kc*16 + hi*8);
  }

  f32x16 ot[4];
  #pragma unroll
  for (int nc = 0; nc < 4; ++nc)
    #pragma unroll
    for (int r = 0; r < 16; ++r) ot[nc][r] = 0.f;
  float m = -1e30f, l = 0.f;

  // stage tile 0
  #pragma unroll
  for (int u = 0; u < 8; ++u) {
    gload16(Kbb + ksrc[u], klds + ldst[u]);
    gload16(Vbb + vsrc[u], vlds + ldst[u]);
  }
  __syncthreads();   // vmcnt(0) drain + barrier

  for (int kt = 0; kt <= qb; ++kt) {
    // ---- QK^T (swapped): D col = q-row, rows = keys
    f32x16 s[2];
    #pragma unroll
    for (int kn = 0; kn < 2; ++kn)
      #pragma unroll
      for (int r = 0; r < 16; ++r) s[kn][r] = 0.f;
    #pragma unroll
    for (int kn = 0; kn < 2; ++kn) {
      const int row = kn*32 + c;
      const int sw = (row & 15) << 4;
      #pragma unroll
      for (int kc = 0; kc < 8; ++kc) {
        const bf16x8 ka = *(const bf16x8*)(klds + row*256 + ((kc*32 + hi*16) ^ sw));
        s[kn] = __builtin_amdgcn_mfma_f32_32x32x16_bf16(ka, qf[kc], s[kn], 0, 0, 0);
      }
    }
    // ---- causal mask: only the diagonal tile (kt == qb)
    if (kt == qb) {
      #pragma unroll
      for (int kn = 0; kn < 2; ++kn)
        #pragma unroll
        for (int r = 0; r < 16; ++r) {
          const int kg_ = kt*64 + kn*32 + (r & 3) + 8*(r >> 2) + 4*hi;
          if (kg_ > qg) s[kn][r] = -1e30f;
        }
    }
    // ---- online softmax (exp2 domain, lane-local per q-row)
    float mx[16];
    #pragma unroll
    for (int r = 0; r < 16; ++r) mx[r] = fmaxf(s[0][r], s[1][r]);
    #pragma unroll
    for (int st = 8; st > 0; st >>= 1)
      #pragma unroll
      for (int r = 0; r < 8; ++r)
        if (r < st) mx[r] = fmaxf(mx[r], mx[r + st]);
    const float pm = fmaxf(mx[0], __shfl_xor(mx[0], 32));
    // T13 defer-max: skip O/l rescale while max growth <= 8 (P <= 2^8, fp32-safe)
    if (!__all(pm - m <= 8.f)) {
      const float mnew = fmaxf(m, pm);
      const float corr = exp2f(m - mnew);
      m = mnew;
      l *= corr;
      #pragma unroll
      for (int nc = 0; nc < 4; ++nc) ot[nc] *= corr;
    }
    float ls = 0.f;
    #pragma unroll
    for (int kn = 0; kn < 2; ++kn)
      #pragma unroll
      for (int r = 0; r < 16; ++r) {
        const float p = exp2f(s[kn][r] - m);
        ls += p;
        s[kn][r] = p;
      }
    l += ls;
    // ---- P^T -> Pl[qrow][key]
    {
      const int swp = (c & 7) << 4;
      #pragma unroll
      for (int kn = 0; kn < 2; ++kn)
        #pragma unroll
        for (int r = 0; r < 16; r += 2) {
          const int key = kn*32 + (r & 3) + 8*(r >> 2) + 4*hi;
          *(unsigned*)(plb + c*128 + ((key*2) ^ swp)) = pack2(s[kn][r], s[kn][r+1]);
        }
    }
    asm volatile("s_waitcnt lgkmcnt(0)" ::: "memory");   // own-wave Pl write->read
    // ---- PV: O^T += V^T . P^T
    #pragma unroll
    for (int kc = 0; kc < 4; ++kc) {
      const bf16x8 pb = *(const bf16x8*)(plb + c*128 + ((kc*32 + hi*16) ^ ((c & 7) << 4)));
      #pragma unroll
      for (int nc = 0; nc < 4; ++nc) {
        const int dim = nc*32 + c;
        const bf16x8 va = *(const bf16x8*)(vlds + dim*128 + ((kc*32 + hi*16) ^ ((dim & 7) << 4)));
        ot[nc] = __builtin_amdgcn_mfma_f32_32x32x16_bf16(va, pb, ot[nc], 0, 0, 0);
      }
    }
    // ---- stage next tile (single buffer: reads must be done block-wide first)
    if (kt < qb) {
      __syncthreads();   // all waves done reading Kl/Vl
      const size_t kto = (size_t)(kt + 1) * 16384;   // 64 rows * 256B
      const int    vto = (kt + 1) * 128;             // 64 keys * 2B within V rows
      #pragma unroll
      for (int u = 0; u < 8; ++u) {
        gload16(Kbb + kto + ksrc[u], klds + ldst[u]);
        gload16(Vbb + vto + vsrc[u], vlds + ldst[u]);
      }
      __syncthreads();   // vmcnt(0) drain: staged data visible
    }
  }

  // ---- epilogue
  const float lt = l + __shfl_xor(l, 32);
  const float inv = 1.f / lt;
  ushort_t* orow = O + (size_t)(b*SEQ + qg) * HIDDEN + h*HD;
  #pragma unroll
  for (int nc = 0; nc < 4; ++nc)
    #pragma unroll
    for (int r = 0; r < 16; r += 2) {
      const int dim = nc*32 + (r & 3) + 8*(r >> 2) + 4*hi;
      *(unsigned*)(orow + dim) = pack2(ot[nc][r]*inv, ot[nc][r+1]*inv);
    }
}

extern "C" void kernel_launch(void* const* d_in, const int* in_sizes, int n_in,
                              void* d_out, int out_size, void* d_ws, size_t ws_size,
                              hipStream_t stream)
{
  (void)in_sizes; (void)n_in; (void)out_size; (void)ws_size;
  const float* H  = (const float*)d_in[0];
  const float* Wq = (const float*)d_in[1];
  const float* Wk = (const float*)d_in[2];
  const float* Wv = (const float*)d_in[3];
  const float* Wo = (const float*)d_in[4];
  float* out = (float*)d_out;

  char* ws = (char*)d_ws;
  ushort_t* QKVb = (ushort_t*)ws;                      // [4096][3072] bf16  25.2 MB
  ushort_t* Hb   = (ushort_t*)(ws + 25165824);         // [4096][2048] bf16  16.8 MB (dead after gemm -> Qb)
  ushort_t* Qb   = Hb;
  ushort_t* Wt   = (ushort_t*)(ws + 41943040);         // [3072][2048] bf16  12.6 MB (reused for Wo)
  ushort_t* Kb   = (ushort_t*)(ws + 54525952);         // [2*4][2048][128]    4.2 MB
  ushort_t* Vtb  = (ushort_t*)(ws + 58720256);         // [2*4][128][2048]    4.2 MB
  ushort_t* Oat  = (ushort_t*)(ws + 62914560);         // [4096][2048] bf16  16.8 MB

  conv_f2b<<<4096, 256, 0, stream>>>(H, Hb, NTOK*HIDDEN/8);
  transpose_f2b<<<dim3(64, 64), 256, 0, stream>>>(Wq, Wt,                     2048, 2048);
  transpose_f2b<<<dim3(16, 64), 256, 0, stream>>>(Wk, Wt + (size_t)2048*2048, 2048, 512);
  transpose_f2b<<<dim3(16, 64), 256, 0, stream>>>(Wv, Wt + (size_t)2560*2048, 2048, 512);

  bt_gemm<true><<<dim3(QKV_LD/128, NTOK/128), 256, 0, stream>>>(Hb, Wt, QKVb, QKV_LD);

  const int rope_total = NTOK * (NH + NKV) * (HD/2);
  rope_conv<<<(rope_total + 255)/256, 256, 0, stream>>>(QKVb, Qb, Kb);
  vt_conv<<<dim3(SEQ/32, 32), 256, 0, stream>>>(QKVb, Vtb);

  attn_mfma4<<<dim3(32, 32), 128, 0, stream>>>(Qb, Kb, Vtb, Oat);

  transpose_f2b<<<dim3(64, 64), 256, 0, stream>>>(Wo, Wt, 2048, 2048);
  bt_gemm<false><<<dim3(HIDDEN/128, NTOK/128), 256, 0, stream>>>(Oat, Wt, out, HIDDEN);
}